// Round 1
// baseline (1793.640 us; speedup 1.0000x reference)
//
#include <hip/hip_runtime.h>

// ---------------- problem constants ----------------
#define T_TOK 2048
#define HIDD  8192
#define NQKV  9216
#define GG    8
#define HH    16
#define DD    64
#define SS    1024
#define BB    2
#define SCALE_ATTN 0.125f   // D^-0.5

typedef __attribute__((ext_vector_type(4))) float f32x4;
typedef __attribute__((ext_vector_type(8))) short bf16x8;

#define GLOBAL_AS __attribute__((address_space(1)))
#define LDS_AS    __attribute__((address_space(3)))

__device__ __forceinline__ void glds16(const void* g, void* l) {
  __builtin_amdgcn_global_load_lds((GLOBAL_AS void*)(g), (LDS_AS void*)(l), 16, 0, 0);
}

__device__ __forceinline__ ushort f2bf(float f) {
  union { float f; unsigned u; } v; v.f = f;
  unsigned u = v.u + 0x7fffu + ((v.u >> 16) & 1u);
  return (ushort)(u >> 16);
}

// ---------------- elementwise fp32 -> bf16 ----------------
__global__ void cvt_bf16_kernel(const float* __restrict__ in, ushort* __restrict__ out, int n4) {
  int i = blockIdx.x * 256 + threadIdx.x;
  if (i >= n4) return;
  float4 v = ((const float4*)in)[i];
  ushort4 o;
  o.x = f2bf(v.x); o.y = f2bf(v.y); o.z = f2bf(v.z); o.w = f2bf(v.w);
  ((ushort4*)out)[i] = o;
}

// ---------------- f32 copy (cache init) ----------------
__global__ void copy_f32_kernel(const float* __restrict__ in, float* __restrict__ out, int n4) {
  int i = blockIdx.x * 256 + threadIdx.x;
  if (i < n4) ((float4*)out)[i] = ((const float4*)in)[i];
}

// ---------------- transpose + convert: in R x C fp32 -> out C x R bf16 ----------------
__global__ __launch_bounds__(256) void transpose_bf16_kernel(
    const float* __restrict__ in, ushort* __restrict__ out, int R, int C)
{
  __shared__ float tile[64][65];
  const int c0 = blockIdx.x * 64, r0 = blockIdx.y * 64;
  const int tid = threadIdx.x;
  const int tx = tid & 15, iy = tid >> 4;
  #pragma unroll
  for (int p = 0; p < 4; ++p) {
    const int i = iy + p * 16;
    const float4 v = *(const float4*)&in[(size_t)(r0 + i) * C + c0 + tx * 4];
    tile[i][tx * 4 + 0] = v.x; tile[i][tx * 4 + 1] = v.y;
    tile[i][tx * 4 + 2] = v.z; tile[i][tx * 4 + 3] = v.w;
  }
  __syncthreads();
  const int r4 = tid & 15, cg = tid >> 4;
  #pragma unroll
  for (int p = 0; p < 4; ++p) {
    const int c = cg + p * 16;
    ushort4 o;
    o.x = f2bf(tile[r4 * 4 + 0][c]);
    o.y = f2bf(tile[r4 * 4 + 1][c]);
    o.z = f2bf(tile[r4 * 4 + 2][c]);
    o.w = f2bf(tile[r4 * 4 + 3][c]);
    *(ushort4*)&out[(size_t)(c0 + c) * R + r0 + r4 * 4] = o;
  }
}

// ---------------- bf16 GEMM v2: 256^2 tile, BK=32, 4-deep ring, counted vmcnt ----------
// C[M,N] = A[M,K] * Bt[N,K]^T + bias[N].
// 512 threads = 8 waves (2 x 4), per-wave 128x64 output (acc[8][4]).
// LDS: 4 buffers x (A 256x32 + B 256x32) bf16 = 128 KB -> 1 block/CU.
// Pipeline: stage tiles t,t+1,t+2 in flight; per iter: vmcnt(8) (completes only
// tile t), raw s_barrier (no drain!), issue stage of t+3 into ring slot (t+3)&3
// (its previous occupant t-1 was fully read before this barrier), 12 ds_read_b128,
// setprio(1) + 32 MFMA + setprio(0). Counted vmcnt = loads span barriers (T4).
__global__ __launch_bounds__(512, 2) void gemm_bt_kernel(
    const ushort* __restrict__ A, const ushort* __restrict__ Bt,
    const float* __restrict__ bias, float* __restrict__ C,
    int M, int N, int K)
{
  __shared__ __align__(16) ushort lds[4 * 16384];   // 128 KB
  const int tid = threadIdx.x;
  const int wid = tid >> 6, lane = tid & 63;
  const int kg = lane >> 4, ln = lane & 15;

  // XCD-aware bijective swizzle (grid count % 8 == 0 for both call sites):
  // chunk of nwg/8 consecutive work units per XCD = one full M-row of tiles
  // -> 4MB A-panel L2-resident per XCD.
  const int nwg = gridDim.x * gridDim.y;
  const int lin = blockIdx.y * gridDim.x + blockIdx.x;
  const int swz = (lin & 7) * (nwg >> 3) + (lin >> 3);
  const int bx = swz % gridDim.x, by = swz / gridDim.x;

  const int m0 = by * 256, n0 = bx * 256;
  const int wm = (wid >> 2) << 7;   // 0 / 128
  const int wn = (wid & 3) << 6;    // 0 / 64 / 128 / 192

  f32x4 acc[8][4] = {};

  // staging: load L = p*512 + tid (p=0,1) covers row = L>>2 (of 256), 16B slot = L&3.
  // linear LDS dest = elem L*8; per-wave uniform base = buf + wid*512 (+4096 for p=1).
  const int r0 = tid >> 2, sl = (tid & 3) * 8;
  const ushort* Ap0 = A  + (size_t)(m0 + r0) * K + sl;
  const ushort* Ap1 = A  + (size_t)(m0 + r0 + 128) * K + sl;
  const ushort* Bp0 = Bt + (size_t)(n0 + r0) * K + sl;
  const ushort* Bp1 = Bt + (size_t)(n0 + r0 + 128) * K + sl;
  ushort* wbA = lds + wid * 512;          // + buf*16384
  ushort* wbB = lds + 8192 + wid * 512;

  const int NT = K >> 5;   // 256 for K=8192

#define STAGE(t) {                                        \
    const int kk = (t) * 32;                              \
    const int bo = ((t) & 3) * 16384;                     \
    glds16(Ap0 + kk, wbA + bo);                           \
    glds16(Ap1 + kk, wbA + bo + 4096);                    \
    glds16(Bp0 + kk, wbB + bo);                           \
    glds16(Bp1 + kk, wbB + bo + 4096);                    \
  }

#define COMPUTE(t) {                                                          \
    const ushort* bufA = lds + ((t) & 3) * 16384;                             \
    const ushort* bufB = bufA + 8192;                                         \
    bf16x8 af[8], bv[4];                                                      \
    _Pragma("unroll")                                                         \
    for (int mi = 0; mi < 8; ++mi)                                            \
      af[mi] = *(const bf16x8*)&bufA[(wm + mi * 16 + ln) * 32 + kg * 8];      \
    _Pragma("unroll")                                                         \
    for (int ni = 0; ni < 4; ++ni)                                            \
      bv[ni] = *(const bf16x8*)&bufB[(wn + ni * 16 + ln) * 32 + kg * 8];      \
    __builtin_amdgcn_s_setprio(1);                                            \
    _Pragma("unroll")                                                         \
    for (int mi = 0; mi < 8; ++mi)                                            \
      _Pragma("unroll")                                                       \
      for (int ni = 0; ni < 4; ++ni)                                          \
        acc[mi][ni] = __builtin_amdgcn_mfma_f32_16x16x32_bf16(                \
            af[mi], bv[ni], acc[mi][ni], 0, 0, 0);                            \
    __builtin_amdgcn_s_setprio(0);                                            \
  }

  STAGE(0); STAGE(1); STAGE(2);   // 12 loads/wave in flight

  for (int t = 0; t < NT - 3; ++t) {
    asm volatile("s_waitcnt vmcnt(8)" ::: "memory");   // tile t landed (wave-local)
    __builtin_amdgcn_s_barrier();                      // all waves' tile t landed;
    asm volatile("" ::: "memory");                     //   all reads of tile t-1 done
    STAGE(t + 3);                                      // overwrite slot of t-1: safe
    COMPUTE(t);
  }
  asm volatile("s_waitcnt vmcnt(8)" ::: "memory");
  __builtin_amdgcn_s_barrier();
  asm volatile("" ::: "memory");
  COMPUTE(NT - 3);
  asm volatile("s_waitcnt vmcnt(4)" ::: "memory");
  __builtin_amdgcn_s_barrier();
  asm volatile("" ::: "memory");
  COMPUTE(NT - 2);
  asm volatile("s_waitcnt vmcnt(0)" ::: "memory");
  __builtin_amdgcn_s_barrier();
  asm volatile("" ::: "memory");
  COMPUTE(NT - 1);

#undef STAGE
#undef COMPUTE

  // epilogue: C = acc + bias   (C/D layout: col=lane&15, row=(lane>>4)*4+reg)
  #pragma unroll
  for (int mi = 0; mi < 8; ++mi) {
    const int row = m0 + wm + mi * 16 + kg * 4;
    #pragma unroll
    for (int ni = 0; ni < 4; ++ni) {
      const int col = n0 + wn + ni * 16 + ln;
      const float bvv = bias[col];
      #pragma unroll
      for (int r = 0; r < 4; ++r)
        C[(size_t)(row + r) * N + col] = acc[mi][ni][r] + bvv;
    }
  }
}

// ---------------- rotary + split + cache scatter ----------------
__global__ void rotary_scatter_kernel(const float* __restrict__ qkv,
                                      const float* __restrict__ cosb, const float* __restrict__ sinb,
                                      const int* __restrict__ slots,
                                      ushort* __restrict__ Qr, ushort* __restrict__ Kr,
                                      ushort* __restrict__ Vr, float* __restrict__ cache)
{
  const int t = blockIdx.x;
  const int b = t >> 10, s = t & 1023;
  const int slot = slots[t];
  for (int j = threadIdx.x; j < GG * 18 * 32; j += 256) {
    const int g = j / 576;
    const int rem = j - g * 576;
    const int head = rem >> 5;
    const int d = rem & 31;
    const float* row = qkv + (size_t)t * NQKV + g * 1152 + head * 64;
    const float x1 = row[d], x2 = row[d + 32];
    const float c = cosb[t * 32 + d], s_ = sinb[t * 32 + d];
    if (head < 16) {
      const size_t o = ((size_t)((b * 128 + g * 16 + head) * 1024 + s)) * 64;
      Qr[o + d]      = f2bf(x1 * c - x2 * s_);
      Qr[o + 32 + d] = f2bf(x2 * c + x1 * s_);
    } else if (head == 16) {
      const float o1 = x1 * c - x2 * s_, o2 = x2 * c + x1 * s_;
      const size_t o = ((size_t)((b * 8 + g) * 1024 + s)) * 64;
      Kr[o + d] = f2bf(o1); Kr[o + 32 + d] = f2bf(o2);
      const size_t co = ((size_t)slot * GG + g) * 64;
      cache[co + d] = o1; cache[co + 32 + d] = o2;
    } else {
      const size_t vo = ((size_t)((b * 8 + g) * 64 + d)) * 1024 + s;
      Vr[vo] = f2bf(x1);
      Vr[vo + (size_t)32 * 1024] = f2bf(x2);
      const size_t co = (size_t)4096 * GG * 64 + ((size_t)slot * GG + g) * 64;
      cache[co + d] = x1; cache[co + 32 + d] = x2;
    }
  }
}

// ---------------- flash attention v2 (causal, GQA) ----------------
__global__ __launch_bounds__(256, 4) void flash_attn_kernel(
    const ushort* __restrict__ Q, const ushort* __restrict__ Kc,
    const ushort* __restrict__ Vc, ushort* __restrict__ O)
{
  const int qb = blockIdx.x;
  const int gh = blockIdx.y;
  const int g  = gh >> 4;
  const int b  = blockIdx.z;
  const int tid = threadIdx.x;
  const int wid = tid >> 6, lane = tid & 63;
  const int kg = lane >> 4, ln = lane & 15;

  __shared__ __align__(16) ushort Ks[64 * 72];
  __shared__ __align__(16) ushort Vt[64 * 72];
  __shared__ __align__(16) ushort Ps[128 * 72];

  bf16x8 qf[2][2];
  #pragma unroll
  for (int st = 0; st < 2; ++st) {
    const int sq = qb * 128 + wid * 32 + st * 16 + ln;
    const size_t qoff = ((size_t)((b * 128 + gh) * 1024 + sq)) * 64;
    qf[st][0] = *(const bf16x8*)&Q[qoff + kg * 8];
    qf[st][1] = *(const bf16x8*)&Q[qoff + 32 + kg * 8];
  }

  f32x4 acc_o[2][4] = {};
  float m_i[2][4], l_i[2][4];
  #pragma unroll
  for (int st = 0; st < 2; ++st)
    #pragma unroll
    for (int r = 0; r < 4; ++r) { m_i[st][r] = -1e30f; l_i[st][r] = 0.f; }

  const size_t kbase = ((size_t)(b * 8 + g) * 1024) * 64;
  const size_t vbase = ((size_t)(b * 8 + g) * 64) * 1024;

  const int n_it = 2 * qb + 2;
  for (int it = 0; it < n_it; ++it) {
    const int t0 = it * 64;
    __syncthreads();
    #pragma unroll
    for (int rep = 0; rep < 2; ++rep) {
      const int idx = rep * 256 + tid;
      const int rr = idx >> 3, c8 = (idx & 7) * 8;
      *(uint4*)&Ks[rr * 72 + c8] = *(const uint4*)&Kc[kbase + (size_t)(t0 + rr) * 64 + c8];
      *(uint4*)&Vt[rr * 72 + c8] = *(const uint4*)&Vc[vbase + (size_t)rr * 1024 + t0 + c8];
    }
    __syncthreads();

    f32x4 sc[2][4];
    #pragma unroll
    for (int tt = 0; tt < 4; ++tt) {
      const bf16x8 kf0 = *(const bf16x8*)&Ks[(tt * 16 + ln) * 72 + kg * 8];
      const bf16x8 kf1 = *(const bf16x8*)&Ks[(tt * 16 + ln) * 72 + 32 + kg * 8];
      #pragma unroll
      for (int st = 0; st < 2; ++st) {
        f32x4 z = {};
        z = __builtin_amdgcn_mfma_f32_16x16x32_bf16(qf[st][0], kf0, z, 0, 0, 0);
        z = __builtin_amdgcn_mfma_f32_16x16x32_bf16(qf[st][1], kf1, z, 0, 0, 0);
        sc[st][tt] = z;
      }
    }

    if (it >= 2 * qb) {
      #pragma unroll
      for (int st = 0; st < 2; ++st) {
        const int srow = qb * 128 + wid * 32 + st * 16 + kg * 4;
        #pragma unroll
        for (int tt = 0; tt < 4; ++tt) {
          const int tg = t0 + tt * 16 + ln;
          #pragma unroll
          for (int r = 0; r < 4; ++r)
            sc[st][tt][r] = (tg <= srow + r) ? sc[st][tt][r] * SCALE_ATTN : -1e30f;
        }
      }
    } else {
      #pragma unroll
      for (int st = 0; st < 2; ++st)
        #pragma unroll
        for (int tt = 0; tt < 4; ++tt)
          #pragma unroll
          for (int r = 0; r < 4; ++r)
            sc[st][tt][r] *= SCALE_ATTN;
    }

    #pragma unroll
    for (int st = 0; st < 2; ++st) {
      float alpha[4];
      #pragma unroll
      for (int r = 0; r < 4; ++r) {
        float mx = fmaxf(fmaxf(sc[st][0][r], sc[st][1][r]), fmaxf(sc[st][2][r], sc[st][3][r]));
        #pragma unroll
        for (int off = 1; off < 16; off <<= 1)
          mx = fmaxf(mx, __shfl_xor(mx, off, 64));
        const float mn = fmaxf(m_i[st][r], mx);
        float rs = 0.f;
        #pragma unroll
        for (int tt = 0; tt < 4; ++tt) {
          const float p = __expf(sc[st][tt][r] - mn);
          sc[st][tt][r] = p; rs += p;
        }
        #pragma unroll
        for (int off = 1; off < 16; off <<= 1)
          rs += __shfl_xor(rs, off, 64);
        alpha[r] = __expf(m_i[st][r] - mn);
        l_i[st][r] = l_i[st][r] * alpha[r] + rs;
        m_i[st][r] = mn;
      }
      #pragma unroll
      for (int dt = 0; dt < 4; ++dt)
        #pragma unroll
        for (int r = 0; r < 4; ++r)
          acc_o[st][dt][r] *= alpha[r];
      #pragma unroll
      for (int tt = 0; tt < 4; ++tt)
        #pragma unroll
        for (int r = 0; r < 4; ++r)
          Ps[(wid * 32 + st * 16 + kg * 4 + r) * 72 + tt * 16 + ln] = f2bf(sc[st][tt][r]);
    }
    __syncthreads();

    #pragma unroll
    for (int c = 0; c < 2; ++c) {
      bf16x8 vf[4];
      #pragma unroll
      for (int dt = 0; dt < 4; ++dt)
        vf[dt] = *(const bf16x8*)&Vt[(dt * 16 + ln) * 72 + c * 32 + kg * 8];
      #pragma unroll
      for (int st = 0; st < 2; ++st) {
        const bf16x8 pf = *(const bf16x8*)&Ps[(wid * 32 + st * 16 + ln) * 72 + c * 32 + kg * 8];
        #pragma unroll
        for (int dt = 0; dt < 4; ++dt)
          acc_o[st][dt] = __builtin_amdgcn_mfma_f32_16x16x32_bf16(pf, vf[dt], acc_o[st][dt], 0, 0, 0);
      }
    }
  }

  #pragma unroll
  for (int st = 0; st < 2; ++st) {
    const int srow = qb * 128 + wid * 32 + st * 16 + kg * 4;
    #pragma unroll
    for (int dt = 0; dt < 4; ++dt) {
      #pragma unroll
      for (int r = 0; r < 4; ++r) {
        const float o = acc_o[st][dt][r] / l_i[st][r];
        O[((size_t)(b * 1024 + srow + r)) * 8192 + gh * 64 + dt * 16 + ln] = f2bf(o);
      }
    }
  }
}

// ---------------- workspace layout (bytes) ----------------
#define WS0_HB   ((size_t)0)                       // hidden bf16 (33.5MB), later attn bf16
#define WS1_WT   ((size_t)33554432)                // wT: w_qkvT (151MB) then w_denseT (134MB)
#define WS2_QKV  ((size_t)(33554432 + 150994944))  // qkv fp32 (75.5MB)
#define WS3_QR   (WS2_QKV + (size_t)75497472)      // q_rot bf16 (33.5MB)
#define WS4_KR   (WS3_QR + (size_t)33554432)       // k_rot bf16 (2MB)
#define WS5_VR   (WS4_KR + (size_t)2097152)        // v^T bf16 (2MB)

extern "C" void kernel_launch(void* const* d_in, const int* in_sizes, int n_in,
                              void* d_out, int out_size, void* d_ws, size_t ws_size,
                              hipStream_t stream) {
  const float* hidden  = (const float*)d_in[0];
  const float* cosb    = (const float*)d_in[1];
  const float* sinb    = (const float*)d_in[2];
  const float* w_qkv   = (const float*)d_in[3];
  const float* b_qkv   = (const float*)d_in[4];
  const float* w_dense = (const float*)d_in[5];
  const float* b_dense = (const float*)d_in[6];
  const float* kv_in   = (const float*)d_in[7];
  const int*   slots   = (const int*)d_in[8];

  float* out = (float*)d_out;
  float* out_cache = out + (size_t)T_TOK * HIDD;

  char* ws = (char*)d_ws;
  ushort* hb   = (ushort*)(ws + WS0_HB);
  ushort* wT   = (ushort*)(ws + WS1_WT);
  float*  qkv  = (float*)(ws + WS2_QKV);
  ushort* qr   = (ushort*)(ws + WS3_QR);
  ushort* kr   = (ushort*)(ws + WS4_KR);
  ushort* vr   = (ushort*)(ws + WS5_VR);
  ushort* attn = hb;  // reuse: hidden_bf16 dead after GEMM1

  // 1. hidden -> bf16
  cvt_bf16_kernel<<<(T_TOK * HIDD / 4 + 255) / 256, 256, 0, stream>>>(hidden, hb, T_TOK * HIDD / 4);
  // 2. w_qkv (HID x NQKV) -> wT (NQKV x HID) bf16
  transpose_bf16_kernel<<<dim3(NQKV / 64, HIDD / 64), 256, 0, stream>>>(w_qkv, wT, HIDD, NQKV);
  // 3. qkv = hb @ wT^T + b_qkv   (M=2048, N=9216, K=8192) — 256^2 pipelined GEMM
  gemm_bt_kernel<<<dim3(NQKV / 256, T_TOK / 256), 512, 0, stream>>>(hb, wT, b_qkv, qkv, T_TOK, NQKV, HIDD);
  // 4. cache init = input kv_cache
  copy_f32_kernel<<<(2 * 4096 * GG * DD / 4 + 255) / 256, 256, 0, stream>>>(kv_in, out_cache, 2 * 4096 * GG * DD / 4);
  // 5. rotary + split + cache scatter
  rotary_scatter_kernel<<<T_TOK, 256, 0, stream>>>(qkv, cosb, sinb, slots, qr, kr, vr, out_cache);
  // 6. w_dense (HID x HID) -> wT (reuse; serialized after GEMM1 by stream order)
  transpose_bf16_kernel<<<dim3(HIDD / 64, HIDD / 64), 256, 0, stream>>>(w_dense, wT, HIDD, HIDD);
  // 7. flash attention v2 -> attn bf16 (T, 8192)
  flash_attn_kernel<<<dim3(SS / 128, GG * HH, BB), 256, 0, stream>>>(qr, kr, vr, attn);
  // 8. out = attn @ wT^T + b_dense   (M=2048, N=8192, K=8192)
  gemm_bt_kernel<<<dim3(HIDD / 256, T_TOK / 256), 512, 0, stream>>>(attn, wT, b_dense, out, T_TOK, HIDD, HIDD);
}

// Round 2
// 1646.161 us; speedup vs baseline: 1.0896x; 1.0896x over previous
//
#include <hip/hip_runtime.h>

// ---------------- problem constants ----------------
#define T_TOK 2048
#define HIDD  8192
#define NQKV  9216
#define GG    8
#define HH    16
#define DD    64
#define SS    1024
#define BB    2
#define SCALE_ATTN 0.125f   // D^-0.5

typedef __attribute__((ext_vector_type(4))) float f32x4;
typedef __attribute__((ext_vector_type(8))) short bf16x8;

#define GLOBAL_AS __attribute__((address_space(1)))
#define LDS_AS    __attribute__((address_space(3)))

__device__ __forceinline__ void glds16(const void* g, void* l) {
  __builtin_amdgcn_global_load_lds((GLOBAL_AS void*)(g), (LDS_AS void*)(l), 16, 0, 0);
}

__device__ __forceinline__ ushort f2bf(float f) {
  union { float f; unsigned u; } v; v.f = f;
  unsigned u = v.u + 0x7fffu + ((v.u >> 16) & 1u);
  return (ushort)(u >> 16);
}

// ---------------- elementwise fp32 -> bf16 ----------------
__global__ void cvt_bf16_kernel(const float* __restrict__ in, ushort* __restrict__ out, int n4) {
  int i = blockIdx.x * 256 + threadIdx.x;
  if (i >= n4) return;
  float4 v = ((const float4*)in)[i];
  ushort4 o;
  o.x = f2bf(v.x); o.y = f2bf(v.y); o.z = f2bf(v.z); o.w = f2bf(v.w);
  ((ushort4*)out)[i] = o;
}

// ---------------- f32 copy (cache init) ----------------
__global__ void copy_f32_kernel(const float* __restrict__ in, float* __restrict__ out, int n4) {
  int i = blockIdx.x * 256 + threadIdx.x;
  if (i < n4) ((float4*)out)[i] = ((const float4*)in)[i];
}

// ---------------- transpose + convert: in R x C fp32 -> out C x R bf16 ----------------
__global__ __launch_bounds__(256) void transpose_bf16_kernel(
    const float* __restrict__ in, ushort* __restrict__ out, int R, int C)
{
  __shared__ float tile[64][65];
  const int c0 = blockIdx.x * 64, r0 = blockIdx.y * 64;
  const int tid = threadIdx.x;
  const int tx = tid & 15, iy = tid >> 4;
  #pragma unroll
  for (int p = 0; p < 4; ++p) {
    const int i = iy + p * 16;
    const float4 v = *(const float4*)&in[(size_t)(r0 + i) * C + c0 + tx * 4];
    tile[i][tx * 4 + 0] = v.x; tile[i][tx * 4 + 1] = v.y;
    tile[i][tx * 4 + 2] = v.z; tile[i][tx * 4 + 3] = v.w;
  }
  __syncthreads();
  const int r4 = tid & 15, cg = tid >> 4;
  #pragma unroll
  for (int p = 0; p < 4; ++p) {
    const int c = cg + p * 16;
    ushort4 o;
    o.x = f2bf(tile[r4 * 4 + 0][c]);
    o.y = f2bf(tile[r4 * 4 + 1][c]);
    o.z = f2bf(tile[r4 * 4 + 2][c]);
    o.w = f2bf(tile[r4 * 4 + 3][c]);
    *(ushort4*)&out[(size_t)(c0 + c) * R + r0 + r4 * 4] = o;
  }
}

// ---------------- bf16 GEMM v3: m201-style 256^2 8-phase schedule ----------------
// C[M,N] = A[M,K] * Bt[N,K]^T + bias[N].
// 512 thr = 8 waves (2M x 4N), per-wave 128x64 out (acc[8][4]), BK=64, 2 K-tiles/iter.
// LDS 128 KB: dbuf d (=tile parity): A halves [2][128][64], B halves [2][128][64],
// XOR-swizzled at 16B granularity: LDS slot (row, g) holds logical (row, g^(row&7)).
// global_load_lds writes linearly -> inverse-swizzle the GLOBAL source (ERRATA #21).
// Per phase: {ds_read_b128 x (12|4|8|0)} + {1 half-tile stage = 2 glds16} -> s_barrier
// -> lgkmcnt(0) -> setprio(1) + 16 MFMA + setprio(0) [-> vmcnt(4) at ph4/ph8] -> s_barrier.
// Stage schedule (iter i computes a=2i in dbuf0 ph1-4, b=2i+1 in dbuf1 ph5-8):
//   ph1: b.Ah0->d1   (d1.A reads of tile b-2 done prev-ph7)
//   ph2: b.Ah1->d1
//   ph3: (a+2).Bh0->d0  (d0.B reads done ph2)
//   ph4: (a+2).Bh1->d0;  vmcnt(4): outstanding={ph3,ph4} => tile b fully landed for ph5
//   ph5: (a+2).Ah0->d0  (d0.A reads done ph3)
//   ph6: (a+2).Ah1->d0
//   ph7: (b+2).Bh0->d1  (d1.B reads done ph6)
//   ph8: (b+2).Bh1->d1;  vmcnt(4): outstanding={ph7,ph8} => tile a+2 landed for next ph1
__global__ __launch_bounds__(512, 2) void gemm_bt_kernel(
    const ushort* __restrict__ A, const ushort* __restrict__ Bt,
    const float* __restrict__ bias, float* __restrict__ C,
    int M, int N, int K)
{
  __shared__ __align__(16) ushort lds[65536];   // 128 KB
  const int tid = threadIdx.x;
  const int wid = tid >> 6, lane = tid & 63;
  const int kg = lane >> 4, ln = lane & 15;

  // XCD-aware bijective swizzle (nwg % 8 == 0 at both call sites)
  const int nwg = gridDim.x * gridDim.y;
  const int lin = blockIdx.y * gridDim.x + blockIdx.x;
  const int swz = (lin & 7) * (nwg >> 3) + (lin >> 3);
  const int bx = swz % gridDim.x, by = swz / gridDim.x;

  const int m0 = by * 256, n0 = bx * 256;
  const int wm = (wid >> 2) << 7;   // 0 / 128
  const int wn = (wid & 3) << 6;    // 0 / 64 / 128 / 192
  const int hA = wm >> 7;           // which A half this wave reads
  const int hB = wn >> 7;           // which B half
  const int brow0 = wn & 64;        // row offset inside B half

  f32x4 acc[8][4] = {};
  bf16x8 af[4][2], bv[4][2];

  // swizzled ds_read column groups (row&7 == ln&7 since rows are base+ln, base%8==0)
  const int x0 = (kg    ) ^ (ln & 7);   // kh=0 group
  const int x1 = (kg + 4) ^ (ln & 7);   // kh=1 group

  // staging geometry: linear LDS slot L = p*512+tid -> row = p*64 + (tid>>3),
  // holds logical group (L&7)^(row&7) -> inverse-swizzled global source group.
  const int r   = tid >> 3;                      // 0..63
  const int grp = (tid & 7) ^ (r & 7);
  const ushort* Abase = A  + (size_t)(m0 + r) * K + grp * 8;
  const ushort* Bbase = Bt + (size_t)(n0 + r) * K + grp * 8;
  ushort* ldsw = lds + wid * 512;                // wave-uniform stage base offset

#define STG_A(kt, h) {                                                  \
    const size_t go = (size_t)((h) * 128) * K + (size_t)(kt) * 64;      \
    ushort* d_ = ldsw + (((kt) & 1) << 15) + ((h) << 13);               \
    glds16(Abase + go, d_);                                             \
    glds16(Abase + go + (size_t)64 * K, d_ + 4096); }
#define STG_B(kt, h) {                                                  \
    const size_t go = (size_t)((h) * 128) * K + (size_t)(kt) * 64;      \
    ushort* d_ = ldsw + 16384 + (((kt) & 1) << 15) + ((h) << 13);       \
    glds16(Bbase + go, d_);                                             \
    glds16(Bbase + go + (size_t)64 * K, d_ + 4096); }

#define LDA8(D, mi0) { _Pragma("unroll") for (int q = 0; q < 4; ++q) {  \
    const int row_ = ((mi0) + q) * 16 + ln;                             \
    const ushort* p_ = lds + ((D) << 15) + hA * 8192 + row_ * 64;       \
    af[q][0] = *(const bf16x8*)&p_[x0 << 3];                            \
    af[q][1] = *(const bf16x8*)&p_[x1 << 3]; } }
#define LDB4(D, ni0) { _Pragma("unroll") for (int q = 0; q < 2; ++q) {  \
    const int row_ = brow0 + ((ni0) + q) * 16 + ln;                     \
    const ushort* p_ = lds + ((D) << 15) + 16384 + hB * 8192 + row_ * 64; \
    bv[(ni0) + q][0] = *(const bf16x8*)&p_[x0 << 3];                    \
    bv[(ni0) + q][1] = *(const bf16x8*)&p_[x1 << 3]; } }

#define MMQ(mi0, ni0) { _Pragma("unroll") for (int q = 0; q < 4; ++q)   \
    _Pragma("unroll") for (int n2 = 0; n2 < 2; ++n2) {                  \
      acc[(mi0)+q][(ni0)+n2] = __builtin_amdgcn_mfma_f32_16x16x32_bf16( \
          af[q][0], bv[(ni0)+n2][0], acc[(mi0)+q][(ni0)+n2], 0, 0, 0);  \
      acc[(mi0)+q][(ni0)+n2] = __builtin_amdgcn_mfma_f32_16x16x32_bf16( \
          af[q][1], bv[(ni0)+n2][1], acc[(mi0)+q][(ni0)+n2], 0, 0, 0); } }

#define BAR   asm volatile("s_barrier" ::: "memory")
#define LGKM  asm volatile("s_waitcnt lgkmcnt(0)" ::: "memory")
#define VMC4  asm volatile("s_waitcnt vmcnt(4)" ::: "memory")
#define VMC0  asm volatile("s_waitcnt vmcnt(0)" ::: "memory")
#define PRIO1 __builtin_amdgcn_s_setprio(1)
#define PRIO0 __builtin_amdgcn_s_setprio(0)

  // prologue: tile0 complete + tile1.B halves; wait tile0 (4 loads outstanding)
  STG_A(0, 0); STG_A(0, 1); STG_B(0, 0); STG_B(0, 1);
  STG_B(1, 0); STG_B(1, 1);
  VMC4; BAR;

  const int NI = K >> 7;   // K/128 iterations, 2 K-tiles each
  for (int i = 0; i < NI - 1; ++i) {
    const int a = 2 * i, b = a + 1;
    // ---- tile a (dbuf0) ----
    LDA8(0, 0); LDB4(0, 0);               // 12 ds_reads
    STG_A(b, 0);
    BAR; LGKM; PRIO1; MMQ(0, 0); PRIO0; BAR;
    LDB4(0, 2);                           // 4
    STG_A(b, 1);
    BAR; LGKM; PRIO1; MMQ(0, 2); PRIO0; BAR;
    LDA8(0, 4);                           // 8
    STG_B(a + 2, 0);
    BAR; LGKM; PRIO1; MMQ(4, 0); PRIO0; BAR;
    STG_B(a + 2, 1);                      // 0 ds_reads
    BAR; LGKM; PRIO1; MMQ(4, 2); PRIO0; VMC4; BAR;
    // ---- tile b (dbuf1) ----
    LDA8(1, 0); LDB4(1, 0);
    STG_A(a + 2, 0);
    BAR; LGKM; PRIO1; MMQ(0, 0); PRIO0; BAR;
    LDB4(1, 2);
    STG_A(a + 2, 1);
    BAR; LGKM; PRIO1; MMQ(0, 2); PRIO0; BAR;
    LDA8(1, 4);
    STG_B(b + 2, 0);
    BAR; LGKM; PRIO1; MMQ(4, 0); PRIO0; BAR;
    STG_B(b + 2, 1);
    BAR; LGKM; PRIO1; MMQ(4, 2); PRIO0; VMC4; BAR;
  }
  // tail iteration: tiles 2*NI-2 (dbuf0) / 2*NI-1 (dbuf1); no future staging
  {
    const int b = 2 * NI - 1;
    LDA8(0, 0); LDB4(0, 0);
    STG_A(b, 0);
    BAR; LGKM; PRIO1; MMQ(0, 0); PRIO0; BAR;
    LDB4(0, 2);
    STG_A(b, 1);
    BAR; LGKM; PRIO1; MMQ(0, 2); PRIO0; BAR;
    LDA8(0, 4);
    BAR; LGKM; PRIO1; MMQ(4, 0); PRIO0; BAR;
    BAR; LGKM; PRIO1; MMQ(4, 2); PRIO0; VMC0; BAR;
    LDA8(1, 0); LDB4(1, 0);
    BAR; LGKM; PRIO1; MMQ(0, 0); PRIO0; BAR;
    LDB4(1, 2);
    BAR; LGKM; PRIO1; MMQ(0, 2); PRIO0; BAR;
    LDA8(1, 4);
    BAR; LGKM; PRIO1; MMQ(4, 0); PRIO0; BAR;
    PRIO1; MMQ(4, 2); PRIO0;
  }

#undef STG_A
#undef STG_B
#undef LDA8
#undef LDB4
#undef MMQ
#undef BAR
#undef LGKM
#undef VMC4
#undef VMC0
#undef PRIO1
#undef PRIO0

  // epilogue: C = acc + bias   (C/D layout: col=lane&15, row=(lane>>4)*4+reg)
  #pragma unroll
  for (int mi = 0; mi < 8; ++mi) {
    const int row = m0 + wm + mi * 16 + kg * 4;
    #pragma unroll
    for (int ni = 0; ni < 4; ++ni) {
      const int col = n0 + wn + ni * 16 + ln;
      const float bvv = bias[col];
      #pragma unroll
      for (int rr = 0; rr < 4; ++rr)
        C[(size_t)(row + rr) * N + col] = acc[mi][ni][rr] + bvv;
    }
  }
}

// ---------------- rotary + split + cache scatter ----------------
__global__ void rotary_scatter_kernel(const float* __restrict__ qkv,
                                      const float* __restrict__ cosb, const float* __restrict__ sinb,
                                      const int* __restrict__ slots,
                                      ushort* __restrict__ Qr, ushort* __restrict__ Kr,
                                      ushort* __restrict__ Vr, float* __restrict__ cache)
{
  const int t = blockIdx.x;
  const int b = t >> 10, s = t & 1023;
  const int slot = slots[t];
  for (int j = threadIdx.x; j < GG * 18 * 32; j += 256) {
    const int g = j / 576;
    const int rem = j - g * 576;
    const int head = rem >> 5;
    const int d = rem & 31;
    const float* row = qkv + (size_t)t * NQKV + g * 1152 + head * 64;
    const float x1 = row[d], x2 = row[d + 32];
    const float c = cosb[t * 32 + d], s_ = sinb[t * 32 + d];
    if (head < 16) {
      const size_t o = ((size_t)((b * 128 + g * 16 + head) * 1024 + s)) * 64;
      Qr[o + d]      = f2bf(x1 * c - x2 * s_);
      Qr[o + 32 + d] = f2bf(x2 * c + x1 * s_);
    } else if (head == 16) {
      const float o1 = x1 * c - x2 * s_, o2 = x2 * c + x1 * s_;
      const size_t o = ((size_t)((b * 8 + g) * 1024 + s)) * 64;
      Kr[o + d] = f2bf(o1); Kr[o + 32 + d] = f2bf(o2);
      const size_t co = ((size_t)slot * GG + g) * 64;
      cache[co + d] = o1; cache[co + 32 + d] = o2;
    } else {
      const size_t vo = ((size_t)((b * 8 + g) * 64 + d)) * 1024 + s;
      Vr[vo] = f2bf(x1);
      Vr[vo + (size_t)32 * 1024] = f2bf(x2);
      const size_t co = (size_t)4096 * GG * 64 + ((size_t)slot * GG + g) * 64;
      cache[co + d] = x1; cache[co + 32 + d] = x2;
    }
  }
}

// ---------------- flash attention v2 (causal, GQA) ----------------
__global__ __launch_bounds__(256, 4) void flash_attn_kernel(
    const ushort* __restrict__ Q, const ushort* __restrict__ Kc,
    const ushort* __restrict__ Vc, ushort* __restrict__ O)
{
  const int qb = blockIdx.x;
  const int gh = blockIdx.y;
  const int g  = gh >> 4;
  const int b  = blockIdx.z;
  const int tid = threadIdx.x;
  const int wid = tid >> 6, lane = tid & 63;
  const int kg = lane >> 4, ln = lane & 15;

  __shared__ __align__(16) ushort Ks[64 * 72];
  __shared__ __align__(16) ushort Vt[64 * 72];
  __shared__ __align__(16) ushort Ps[128 * 72];

  bf16x8 qf[2][2];
  #pragma unroll
  for (int st = 0; st < 2; ++st) {
    const int sq = qb * 128 + wid * 32 + st * 16 + ln;
    const size_t qoff = ((size_t)((b * 128 + gh) * 1024 + sq)) * 64;
    qf[st][0] = *(const bf16x8*)&Q[qoff + kg * 8];
    qf[st][1] = *(const bf16x8*)&Q[qoff + 32 + kg * 8];
  }

  f32x4 acc_o[2][4] = {};
  float m_i[2][4], l_i[2][4];
  #pragma unroll
  for (int st = 0; st < 2; ++st)
    #pragma unroll
    for (int r = 0; r < 4; ++r) { m_i[st][r] = -1e30f; l_i[st][r] = 0.f; }

  const size_t kbase = ((size_t)(b * 8 + g) * 1024) * 64;
  const size_t vbase = ((size_t)(b * 8 + g) * 64) * 1024;

  const int n_it = 2 * qb + 2;
  for (int it = 0; it < n_it; ++it) {
    const int t0 = it * 64;
    __syncthreads();
    #pragma unroll
    for (int rep = 0; rep < 2; ++rep) {
      const int idx = rep * 256 + tid;
      const int rr = idx >> 3, c8 = (idx & 7) * 8;
      *(uint4*)&Ks[rr * 72 + c8] = *(const uint4*)&Kc[kbase + (size_t)(t0 + rr) * 64 + c8];
      *(uint4*)&Vt[rr * 72 + c8] = *(const uint4*)&Vc[vbase + (size_t)rr * 1024 + t0 + c8];
    }
    __syncthreads();

    f32x4 sc[2][4];
    #pragma unroll
    for (int tt = 0; tt < 4; ++tt) {
      const bf16x8 kf0 = *(const bf16x8*)&Ks[(tt * 16 + ln) * 72 + kg * 8];
      const bf16x8 kf1 = *(const bf16x8*)&Ks[(tt * 16 + ln) * 72 + 32 + kg * 8];
      #pragma unroll
      for (int st = 0; st < 2; ++st) {
        f32x4 z = {};
        z = __builtin_amdgcn_mfma_f32_16x16x32_bf16(qf[st][0], kf0, z, 0, 0, 0);
        z = __builtin_amdgcn_mfma_f32_16x16x32_bf16(qf[st][1], kf1, z, 0, 0, 0);
        sc[st][tt] = z;
      }
    }

    if (it >= 2 * qb) {
      #pragma unroll
      for (int st = 0; st < 2; ++st) {
        const int srow = qb * 128 + wid * 32 + st * 16 + kg * 4;
        #pragma unroll
        for (int tt = 0; tt < 4; ++tt) {
          const int tg = t0 + tt * 16 + ln;
          #pragma unroll
          for (int r = 0; r < 4; ++r)
            sc[st][tt][r] = (tg <= srow + r) ? sc[st][tt][r] * SCALE_ATTN : -1e30f;
        }
      }
    } else {
      #pragma unroll
      for (int st = 0; st < 2; ++st)
        #pragma unroll
        for (int tt = 0; tt < 4; ++tt)
          #pragma unroll
          for (int r = 0; r < 4; ++r)
            sc[st][tt][r] *= SCALE_ATTN;
    }

    #pragma unroll
    for (int st = 0; st < 2; ++st) {
      float alpha[4];
      #pragma unroll
      for (int r = 0; r < 4; ++r) {
        float mx = fmaxf(fmaxf(sc[st][0][r], sc[st][1][r]), fmaxf(sc[st][2][r], sc[st][3][r]));
        #pragma unroll
        for (int off = 1; off < 16; off <<= 1)
          mx = fmaxf(mx, __shfl_xor(mx, off, 64));
        const float mn = fmaxf(m_i[st][r], mx);
        float rs = 0.f;
        #pragma unroll
        for (int tt = 0; tt < 4; ++tt) {
          const float p = __expf(sc[st][tt][r] - mn);
          sc[st][tt][r] = p; rs += p;
        }
        #pragma unroll
        for (int off = 1; off < 16; off <<= 1)
          rs += __shfl_xor(rs, off, 64);
        alpha[r] = __expf(m_i[st][r] - mn);
        l_i[st][r] = l_i[st][r] * alpha[r] + rs;
        m_i[st][r] = mn;
      }
      #pragma unroll
      for (int dt = 0; dt < 4; ++dt)
        #pragma unroll
        for (int r = 0; r < 4; ++r)
          acc_o[st][dt][r] *= alpha[r];
      #pragma unroll
      for (int tt = 0; tt < 4; ++tt)
        #pragma unroll
        for (int r = 0; r < 4; ++r)
          Ps[(wid * 32 + st * 16 + kg * 4 + r) * 72 + tt * 16 + ln] = f2bf(sc[st][tt][r]);
    }
    __syncthreads();

    #pragma unroll
    for (int c = 0; c < 2; ++c) {
      bf16x8 vf[4];
      #pragma unroll
      for (int dt = 0; dt < 4; ++dt)
        vf[dt] = *(const bf16x8*)&Vt[(dt * 16 + ln) * 72 + c * 32 + kg * 8];
      #pragma unroll
      for (int st = 0; st < 2; ++st) {
        const bf16x8 pf = *(const bf16x8*)&Ps[(wid * 32 + st * 16 + ln) * 72 + c * 32 + kg * 8];
        #pragma unroll
        for (int dt = 0; dt < 4; ++dt)
          acc_o[st][dt] = __builtin_amdgcn_mfma_f32_16x16x32_bf16(pf, vf[dt], acc_o[st][dt], 0, 0, 0);
      }
    }
  }

  #pragma unroll
  for (int st = 0; st < 2; ++st) {
    const int srow = qb * 128 + wid * 32 + st * 16 + kg * 4;
    #pragma unroll
    for (int dt = 0; dt < 4; ++dt) {
      #pragma unroll
      for (int r = 0; r < 4; ++r) {
        const float o = acc_o[st][dt][r] / l_i[st][r];
        O[((size_t)(b * 1024 + srow + r)) * 8192 + gh * 64 + dt * 16 + ln] = f2bf(o);
      }
    }
  }
}

// ---------------- workspace layout (bytes) ----------------
#define WS0_HB   ((size_t)0)                       // hidden bf16 (33.5MB), later attn bf16
#define WS1_WT   ((size_t)33554432)                // wT: w_qkvT (151MB) then w_denseT (134MB)
#define WS2_QKV  ((size_t)(33554432 + 150994944))  // qkv fp32 (75.5MB)
#define WS3_QR   (WS2_QKV + (size_t)75497472)      // q_rot bf16 (33.5MB)
#define WS4_KR   (WS3_QR + (size_t)33554432)       // k_rot bf16 (2MB)
#define WS5_VR   (WS4_KR + (size_t)2097152)        // v^T bf16 (2MB)

extern "C" void kernel_launch(void* const* d_in, const int* in_sizes, int n_in,
                              void* d_out, int out_size, void* d_ws, size_t ws_size,
                              hipStream_t stream) {
  const float* hidden  = (const float*)d_in[0];
  const float* cosb    = (const float*)d_in[1];
  const float* sinb    = (const float*)d_in[2];
  const float* w_qkv   = (const float*)d_in[3];
  const float* b_qkv   = (const float*)d_in[4];
  const float* w_dense = (const float*)d_in[5];
  const float* b_dense = (const float*)d_in[6];
  const float* kv_in   = (const float*)d_in[7];
  const int*   slots   = (const int*)d_in[8];

  float* out = (float*)d_out;
  float* out_cache = out + (size_t)T_TOK * HIDD;

  char* ws = (char*)d_ws;
  ushort* hb   = (ushort*)(ws + WS0_HB);
  ushort* wT   = (ushort*)(ws + WS1_WT);
  float*  qkv  = (float*)(ws + WS2_QKV);
  ushort* qr   = (ushort*)(ws + WS3_QR);
  ushort* kr   = (ushort*)(ws + WS4_KR);
  ushort* vr   = (ushort*)(ws + WS5_VR);
  ushort* attn = hb;  // reuse: hidden_bf16 dead after GEMM1

  // 1. hidden -> bf16
  cvt_bf16_kernel<<<(T_TOK * HIDD / 4 + 255) / 256, 256, 0, stream>>>(hidden, hb, T_TOK * HIDD / 4);
  // 2. w_qkv (HID x NQKV) -> wT (NQKV x HID) bf16
  transpose_bf16_kernel<<<dim3(NQKV / 64, HIDD / 64), 256, 0, stream>>>(w_qkv, wT, HIDD, NQKV);
  // 3. qkv = hb @ wT^T + b_qkv   (M=2048, N=9216, K=8192) — 8-phase 256^2 GEMM
  gemm_bt_kernel<<<dim3(NQKV / 256, T_TOK / 256), 512, 0, stream>>>(hb, wT, b_qkv, qkv, T_TOK, NQKV, HIDD);
  // 4. cache init = input kv_cache
  copy_f32_kernel<<<(2 * 4096 * GG * DD / 4 + 255) / 256, 256, 0, stream>>>(kv_in, out_cache, 2 * 4096 * GG * DD / 4);
  // 5. rotary + split + cache scatter
  rotary_scatter_kernel<<<T_TOK, 256, 0, stream>>>(qkv, cosb, sinb, slots, qr, kr, vr, out_cache);
  // 6. w_dense (HID x HID) -> wT (reuse; serialized after GEMM1 by stream order)
  transpose_bf16_kernel<<<dim3(HIDD / 64, HIDD / 64), 256, 0, stream>>>(w_dense, wT, HIDD, HIDD);
  // 7. flash attention v2 -> attn bf16 (T, 8192)
  flash_attn_kernel<<<dim3(SS / 128, GG * HH, BB), 256, 0, stream>>>(qr, kr, vr, attn);
  // 8. out = attn @ wT^T + b_dense   (M=2048, N=8192, K=8192)
  gemm_bt_kernel<<<dim3(HIDD / 256, T_TOK / 256), 512, 0, stream>>>(attn, wT, b_dense, out, T_TOK, HIDD, HIDD);
}